// Round 7
// baseline (64.836 us; speedup 1.0000x reference)
//
#include <hip/hip_runtime.h>

#define BB 8
#define MM 2048
#define HH 1024
#define THRESH 0.99f
#define BMH ((size_t)BB * MM * HH)
#define BM (BB * MM)
#define CHUNK 16
#define NBLK (BM / CHUNK)   // 1024 blocks

typedef float f32x4 __attribute__((ext_vector_type(4)));

__device__ inline f32x4 ntload4(const float* p) {
    return __builtin_nontemporal_load((const f32x4*)p);
}
__device__ inline void ntstore4(float* p, f32x4 v) {
    __builtin_nontemporal_store(v, (f32x4*)p);
}
__device__ inline f32x4 ld4(const float* p) { return *(const f32x4*)p; }

// ---------------------------------------------------------------------------
// K_dot: p_ws[t] = sigmoid(x[b, rank[t]] . p_w + p_b) for run tokens, else 0.
// Per-block redundant prefix of `run` gives rank. ~32MB HBM read total.
// ---------------------------------------------------------------------------
__global__ __launch_bounds__(256) void dotp_kernel(
    const float* __restrict__ x, const int* __restrict__ run,
    const float* __restrict__ p_w, const float* __restrict__ p_b,
    float* __restrict__ p_ws) {
    __shared__ int wsum[4];
    __shared__ int cflag[CHUNK];
    __shared__ int crank[CHUNK];

    const int t0 = blockIdx.x * CHUNK;
    const int b  = t0 >> 11;
    const int m0 = t0 & (MM - 1);
    const int* rrow = run + b * MM;
    const int tid  = threadIdx.x;
    const int wave = tid >> 6;
    const int lane = tid & 63;

    f32x4 wv[4];
#pragma unroll
    for (int j = 0; j < 4; ++j) wv[j] = ld4(p_w + j * 256 + lane * 4);

    int s = 0;
    for (int i = tid; i < m0; i += 256) s += (rrow[i] != 0) ? 1 : 0;
#pragma unroll
    for (int off = 32; off > 0; off >>= 1) s += __shfl_xor(s, off, 64);
    if (lane == 0) wsum[wave] = s;
    if (tid < CHUNK) cflag[tid] = (rrow[m0 + tid] != 0) ? 1 : 0;
    __syncthreads();
    const int base0 = wsum[0] + wsum[1] + wsum[2] + wsum[3];
    if (tid < CHUNK) {
        int r = base0;
#pragma unroll
        for (int i = 0; i < CHUNK; ++i) r += (i <= tid) ? cflag[i] : 0;
        crank[tid] = r - 1;
    }
    __syncthreads();

#pragma unroll
    for (int q = 0; q < 4; ++q) {
        const int ti = wave * 4 + q;
        const int t  = t0 + ti;
        const bool r = (cflag[ti] != 0);
        float dot = 0.f;
        if (r) {
            const float* xrow = x + ((size_t)(b * MM + crank[ti])) * HH;
#pragma unroll
            for (int j = 0; j < 4; ++j) {
                const int idx = j * 256 + lane * 4;
                const f32x4 hv = ld4(xrow + idx);
                dot += hv.x * wv[j].x + hv.y * wv[j].y +
                       hv.z * wv[j].z + hv.w * wv[j].w;
            }
        }
#pragma unroll
        for (int off = 32; off > 0; off >>= 1) dot += __shfl_xor(dot, off, 64);
        if (lane == 0)
            p_ws[t] = r ? (1.f / (1.f + expf(-(dot + p_b[0])))) : 0.f;
    }
}

// ---------------------------------------------------------------------------
// K_main: per-block redundant scan over (run, acc_p, p_ws) reconstructs
// rank, rank2, cnt locally. Then ONE heavy pass: x row read once into regs,
// serving both the weighted_h update and the h_packed scatter; pad tail.
// ---------------------------------------------------------------------------
__global__ __launch_bounds__(256) void main2_kernel(
    const float* __restrict__ x, const int* __restrict__ run,
    const float* __restrict__ acc_p, const float* __restrict__ weighted_h,
    const float* __restrict__ remainders, const int* __restrict__ exit_,
    const int* __restrict__ updates, const float* __restrict__ pad_h,
    const float* __restrict__ p_ws,
    float* __restrict__ out_hpacked, float* __restrict__ out_wh,
    float* __restrict__ out_accp, float* __restrict__ out_rem,
    float* __restrict__ out_run, float* __restrict__ out_exit) {
    __shared__ int wsumR[4], wsumN[4], wsumA[4];
    __shared__ int cflag[CHUNK], cnew[CHUNK];
    __shared__ int crank[CHUNK], crank2[CHUNK];

    const int t0 = blockIdx.x * CHUNK;
    const int b  = t0 >> 11;
    const int m0 = t0 & (MM - 1);
    const int* rrow   = run   + b * MM;
    const float* arow = acc_p + b * MM;
    const float* prow = p_ws  + b * MM;
    const int tid  = threadIdx.x;
    const int wave = tid >> 6;
    const int lane = tid & 63;

    // hoisted pad_h fragment
    f32x4 pv[4];
#pragma unroll
    for (int j = 0; j < 4; ++j) pv[j] = ld4(pad_h + j * 256 + lane * 4);

    // full-row pass: run count prefix, run_new count prefix, run_new total
    int sR = 0, sN = 0, sA = 0;
#pragma unroll
    for (int k = 0; k < MM / 256; ++k) {
        const int i = tid + k * 256;
        const int f  = (rrow[i] != 0) ? 1 : 0;
        const int mc = (f && (arow[i] + prow[i] < THRESH)) ? 1 : 0;
        sA += mc;
        if (i < m0) { sR += f; sN += mc; }
    }
#pragma unroll
    for (int off = 32; off > 0; off >>= 1) {
        sR += __shfl_xor(sR, off, 64);
        sN += __shfl_xor(sN, off, 64);
        sA += __shfl_xor(sA, off, 64);
    }
    if (lane == 0) { wsumR[wave] = sR; wsumN[wave] = sN; wsumA[wave] = sA; }
    if (tid < CHUNK) {
        const int f  = (rrow[m0 + tid] != 0) ? 1 : 0;
        const int mc = (f && (arow[m0 + tid] + prow[m0 + tid] < THRESH)) ? 1 : 0;
        cflag[tid] = f;
        cnew[tid]  = mc;
    }
    __syncthreads();
    const int baseR = wsumR[0] + wsumR[1] + wsumR[2] + wsumR[3];
    const int baseN = wsumN[0] + wsumN[1] + wsumN[2] + wsumN[3];
    const int cnt   = wsumA[0] + wsumA[1] + wsumA[2] + wsumA[3];
    if (tid < CHUNK) {
        int r = baseR, n = baseN;
#pragma unroll
        for (int i = 0; i < CHUNK; ++i) {
            r += (i <= tid) ? cflag[i] : 0;
            n += (i <= tid) ? cnew[i]  : 0;
        }
        crank[tid]  = r - 1;
        crank2[tid] = n - 1;
    }
    __syncthreads();

#pragma unroll
    for (int q = 0; q < 4; ++q) {
        const int ti = wave * 4 + q;
        const int t  = t0 + ti;
        const int m  = m0 + ti;
        const bool r  = (cflag[ti] != 0);
        const bool mc = (cnew[ti] != 0);
        const bool me = r && !mc;
        const float p  = prow[m];
        const float ap = arow[m];
        const float upd = mc ? p : (me ? (1.f - ap) : 0.f);
        const float ap_new = mc ? (ap + p) : ap;

        const float* xrow  = x + ((size_t)(b * MM + crank[ti])) * HH;
        float* dst = out_hpacked + ((size_t)(b * MM + crank2[ti])) * HH;
        const float* whrow = weighted_h + (size_t)t * HH;
        float* orow = out_wh + (size_t)t * HH;

#pragma unroll
        for (int j = 0; j < 4; ++j) {
            const int idx = j * 256 + lane * 4;
            const f32x4 w4 = ntload4(whrow + idx);
            f32x4 hv = (f32x4)(0.f);
            if (r) hv = ld4(xrow + idx);
            ntstore4(orow + idx, hv * upd + w4);
            if (mc) ntstore4(dst + idx, hv);
        }
        if (lane == 0) {
            out_accp[t] = ap_new;
            out_rem[t]  = remainders[t] + (me ? (1.f - ap_new) : 0.f);
            out_run[t]  = mc ? 1.f : 0.f;
            out_exit[t] = (float)(exit_[t] + (me ? (updates[0] + 1) : 0));
        }
        if (m >= cnt) {
            float* padrow = out_hpacked + (size_t)t * HH;
#pragma unroll
            for (int j = 0; j < 4; ++j) {
                const int idx = j * 256 + lane * 4;
                ntstore4(padrow + idx, pv[j]);
            }
        }
    }
}

extern "C" void kernel_launch(void* const* d_in, const int* in_sizes, int n_in,
                              void* d_out, int out_size, void* d_ws, size_t ws_size,
                              hipStream_t stream) {
    const float* x          = (const float*)d_in[0];
    const int*   run        = (const int*)d_in[1];
    const float* acc_p      = (const float*)d_in[2];
    const float* weighted_h = (const float*)d_in[3];
    const float* remainders = (const float*)d_in[4];
    const int*   exit_      = (const int*)d_in[5];
    const int*   updates    = (const int*)d_in[6];
    const float* pad_h      = (const float*)d_in[7];
    const float* p_w        = (const float*)d_in[8];
    const float* p_b        = (const float*)d_in[9];

    float* out = (float*)d_out;
    float* out_hpacked = out;                    // [B,M,H]
    float* out_wh      = out + BMH;              // [B,M,H]
    float* out_accp    = out + 2 * BMH;          // [B,M,1]
    float* out_rem     = out_accp + BM;          // [B,M,1]
    float* out_run     = out_rem + BM;           // [B,M]
    float* out_exit    = out_run + BM;           // [B,M,1]

    float* p_ws = (float*)d_ws;   // [B*M] sigmoid probabilities

    dotp_kernel<<<NBLK, 256, 0, stream>>>(x, run, p_w, p_b, p_ws);

    main2_kernel<<<NBLK, 256, 0, stream>>>(x, run, acc_p, weighted_h, remainders,
                                           exit_, updates, pad_h, p_ws,
                                           out_hpacked, out_wh, out_accp,
                                           out_rem, out_run, out_exit);
}

// Round 8
// 57.312 us; speedup vs baseline: 1.1313x; 1.1313x over previous
//
#include <hip/hip_runtime.h>

#define BB 8
#define MM 2048
#define HH 1024
#define THRESH 0.99f
#define BMH ((size_t)BB * MM * HH)
#define BM (BB * MM)
#define CHUNK 16
#define CPR (MM / CHUNK)     // 128 chunks per batch row
#define NBLK (BM / CHUNK)    // 1024 blocks = 4/CU x 256 CU (co-resident)
#define RDY 0x40000000

typedef float f32x4 __attribute__((ext_vector_type(4)));

__device__ inline f32x4 ntload4(const float* p) {
    return __builtin_nontemporal_load((const f32x4*)p);
}
__device__ inline void ntstore4(float* p, f32x4 v) {
    __builtin_nontemporal_store(v, (f32x4*)p);
}
__device__ inline f32x4 ld4(const float* p) { return *(const f32x4*)p; }

// ---------------------------------------------------------------------------
// Single persistent kernel. Block = 16 tokens of one batch row.
// Phase1: local run-prefix -> rank; gather x row; dot+sigmoid; wh update;
//         scalar outputs; publish chunk run_new mask (ready-flagged word).
// Handshake: spin until all 128 chunk masks of this row are published.
// Phase2: popc-prefix -> rank2/cnt; pack scatter (x from warm L1/L2); pad.
// __launch_bounds__(256,4): VGPR<=128 => 4 blocks/CU => all 1024 resident.
// ---------------------------------------------------------------------------
__global__ __launch_bounds__(256, 4) void act_kernel(
    const float* __restrict__ x, const int* __restrict__ run,
    const float* __restrict__ acc_p, const float* __restrict__ weighted_h,
    const float* __restrict__ remainders, const int* __restrict__ exit_,
    const int* __restrict__ updates, const float* __restrict__ pad_h,
    const float* __restrict__ p_w, const float* __restrict__ p_b,
    float* __restrict__ out_hpacked, float* __restrict__ out_wh,
    float* __restrict__ out_accp, float* __restrict__ out_rem,
    float* __restrict__ out_run, float* __restrict__ out_exit,
    int* __restrict__ mask_ws) {
    __shared__ int wsum[4];
    __shared__ int cflag[CHUNK], cnew[CHUNK], crank[CHUNK], crank2[CHUNK];
    __shared__ int rowmask[CPR];

    const int chunk = blockIdx.x;
    const int t0  = chunk * CHUNK;       // global token base
    const int b   = t0 >> 11;
    const int m0  = t0 & (MM - 1);
    const int myc = chunk & (CPR - 1);
    const int* rrow = run + b * MM;
    const int tid  = threadIdx.x;
    const int wave = tid >> 6;
    const int lane = tid & 63;

    // hoisted p_w fragment (reused by all 4 tokens of this wave)
    f32x4 wv[4];
#pragma unroll
    for (int j = 0; j < 4; ++j) wv[j] = ld4(p_w + j * 256 + lane * 4);

    // exclusive prefix count of run[b, 0..m0)
    int s = 0;
    for (int i = tid; i < m0; i += 256) s += (rrow[i] != 0) ? 1 : 0;
#pragma unroll
    for (int off = 32; off > 0; off >>= 1) s += __shfl_xor(s, off, 64);
    if (lane == 0) wsum[wave] = s;
    if (tid < CHUNK) cflag[tid] = (rrow[m0 + tid] != 0) ? 1 : 0;
    __syncthreads();
    const int base0 = wsum[0] + wsum[1] + wsum[2] + wsum[3];
    if (tid < CHUNK) {
        int r = base0;
#pragma unroll
        for (int i = 0; i < CHUNK; ++i) r += (i <= tid) ? cflag[i] : 0;
        crank[tid] = r - 1;
    }
    __syncthreads();

    // ---- Phase 1 ----
    const float pb = p_b[0];
    const int upd1 = updates[0] + 1;
#pragma unroll
    for (int q = 0; q < 4; ++q) {
        const int ti = wave * 4 + q;
        const int t  = t0 + ti;
        const bool r = (cflag[ti] != 0);
        f32x4 hv[4];
        float dot = 0.f;
        if (r) {
            const float* xrow = x + ((size_t)(b * MM + crank[ti])) * HH;
#pragma unroll
            for (int j = 0; j < 4; ++j) {
                const int idx = j * 256 + lane * 4;
                hv[j] = ld4(xrow + idx);
                dot += hv[j].x * wv[j].x + hv[j].y * wv[j].y +
                       hv[j].z * wv[j].z + hv[j].w * wv[j].w;
            }
        } else {
#pragma unroll
            for (int j = 0; j < 4; ++j) hv[j] = (f32x4)(0.f);
        }
#pragma unroll
        for (int off = 32; off > 0; off >>= 1) dot += __shfl_xor(dot, off, 64);

        const float p = r ? (1.f / (1.f + expf(-(dot + pb)))) : 0.f;
        const float ap = acc_p[t];
        const bool mc = r && ((ap + p) < THRESH);
        const bool me = r && !mc;
        const float upd = mc ? p : (me ? (1.f - ap) : 0.f);
        const float ap_new = mc ? (ap + p) : ap;

        const float* whrow = weighted_h + (size_t)t * HH;
        float* orow = out_wh + (size_t)t * HH;
#pragma unroll
        for (int j = 0; j < 4; ++j) {
            const int idx = j * 256 + lane * 4;
            const f32x4 w4 = ntload4(whrow + idx);
            ntstore4(orow + idx, hv[j] * upd + w4);
        }
        if (lane == 0) {
            out_accp[t] = ap_new;
            out_rem[t]  = remainders[t] + (me ? (1.f - ap_new) : 0.f);
            out_run[t]  = mc ? 1.f : 0.f;
            out_exit[t] = (float)(exit_[t] + (me ? upd1 : 0));
            cnew[ti] = mc ? 1 : 0;
        }
    }
    __syncthreads();

    // ---- publish this chunk's run_new mask (payload == atomic word) ----
    if (tid == 0) {
        int m16 = 0;
#pragma unroll
        for (int i = 0; i < CHUNK; ++i) m16 |= cnew[i] << i;
        __hip_atomic_store(mask_ws + chunk, RDY | m16, __ATOMIC_RELAXED,
                           __HIP_MEMORY_SCOPE_AGENT);
    }

    // ---- spin: collect all 128 masks of this row ----
    if (tid < CPR) {
        const int* src = mask_ws + b * CPR + tid;
        int v;
        while (((v = __hip_atomic_load(src, __ATOMIC_RELAXED,
                                       __HIP_MEMORY_SCOPE_AGENT)) & RDY) == 0) {
            __builtin_amdgcn_s_sleep(4);
        }
        rowmask[tid] = v & 0xFFFF;
    }
    __syncthreads();

    // ---- rank2 / cnt from popcount prefix (uniform loop) ----
    int baseN = 0, cnt = 0;
    for (int c = 0; c < CPR; ++c) {
        const int pc = __popc(rowmask[c]);
        cnt += pc;
        baseN += (c < myc) ? pc : 0;
    }
    if (tid < CHUNK) {
        int n = baseN;
#pragma unroll
        for (int i = 0; i < CHUNK; ++i) n += (i <= tid) ? cnew[i] : 0;
        crank2[tid] = n - 1;
    }
    __syncthreads();

    // ---- Phase 2: pack scatter + pad tail ----
    f32x4 pv[4];
#pragma unroll
    for (int j = 0; j < 4; ++j) pv[j] = ld4(pad_h + j * 256 + lane * 4);

#pragma unroll
    for (int q = 0; q < 4; ++q) {
        const int ti = wave * 4 + q;
        const int t  = t0 + ti;
        const int m  = m0 + ti;
        if (cnew[ti] != 0) {
            const float* src = x + ((size_t)(b * MM + crank[ti])) * HH;
            float* dst = out_hpacked + ((size_t)(b * MM + crank2[ti])) * HH;
#pragma unroll
            for (int j = 0; j < 4; ++j) {
                const int idx = j * 256 + lane * 4;
                ntstore4(dst + idx, ld4(src + idx));
            }
        }
        if (m >= cnt) {
            float* prow = out_hpacked + (size_t)t * HH;
#pragma unroll
            for (int j = 0; j < 4; ++j) {
                const int idx = j * 256 + lane * 4;
                ntstore4(prow + idx, pv[j]);
            }
        }
    }
}

extern "C" void kernel_launch(void* const* d_in, const int* in_sizes, int n_in,
                              void* d_out, int out_size, void* d_ws, size_t ws_size,
                              hipStream_t stream) {
    const float* x          = (const float*)d_in[0];
    const int*   run        = (const int*)d_in[1];
    const float* acc_p      = (const float*)d_in[2];
    const float* weighted_h = (const float*)d_in[3];
    const float* remainders = (const float*)d_in[4];
    const int*   exit_      = (const int*)d_in[5];
    const int*   updates    = (const int*)d_in[6];
    const float* pad_h      = (const float*)d_in[7];
    const float* p_w        = (const float*)d_in[8];
    const float* p_b        = (const float*)d_in[9];

    float* out = (float*)d_out;
    float* out_hpacked = out;                    // [B,M,H]
    float* out_wh      = out + BMH;              // [B,M,H]
    float* out_accp    = out + 2 * BMH;          // [B,M,1]
    float* out_rem     = out_accp + BM;          // [B,M,1]
    float* out_run     = out_rem + BM;           // [B,M]
    float* out_exit    = out_run + BM;           // [B,M,1]

    int* mask_ws = (int*)d_ws;   // [NBLK] ready-flagged run_new masks

    hipMemsetAsync(mask_ws, 0, NBLK * sizeof(int), stream);

    act_kernel<<<NBLK, 256, 0, stream>>>(x, run, acc_p, weighted_h, remainders,
                                         exit_, updates, pad_h, p_w, p_b,
                                         out_hpacked, out_wh, out_accp, out_rem,
                                         out_run, out_exit, mask_ws);
}

// Round 9
// 48.848 us; speedup vs baseline: 1.3273x; 1.1733x over previous
//
#include <hip/hip_runtime.h>

#define BB 8
#define MM 2048
#define HH 1024
#define THRESH 0.99f
#define BMH ((size_t)BB * MM * HH)
#define BM (BB * MM)
#define CHUNK 8
#define NBLK (BM / CHUNK)   // 2048 blocks = 8/CU x 256 CU (full occupancy @ VGPR<=64)

typedef float f32x4 __attribute__((ext_vector_type(4)));

__device__ inline f32x4 ntload4(const float* p) {
    return __builtin_nontemporal_load((const f32x4*)p);
}
__device__ inline void ntstore4(float* p, f32x4 v) {
    __builtin_nontemporal_store(v, (f32x4*)p);
}
__device__ inline f32x4 ld4(const float* p) { return *(const f32x4*)p; }

// ---------------------------------------------------------------------------
// P1: redundant prefix of `run` -> rank; dot + sigmoid + scalars + wh update.
// Each block owns 8 contiguous tokens of one batch row; 4 waves x 2 tokens.
// __launch_bounds__(256,8): VGPR<=64 -> 8 blocks/CU -> 32 waves/CU.
// ---------------------------------------------------------------------------
__global__ __launch_bounds__(256, 8) void phase1_kernel(
    const float* __restrict__ x, const int* __restrict__ run,
    const float* __restrict__ acc_p, const float* __restrict__ weighted_h,
    const float* __restrict__ remainders, const int* __restrict__ exit_,
    const int* __restrict__ updates, const float* __restrict__ p_w,
    const float* __restrict__ p_b,
    float* __restrict__ out_wh, float* __restrict__ out_accp,
    float* __restrict__ out_rem, float* __restrict__ out_run,
    float* __restrict__ out_exit, int* __restrict__ run_new_i,
    int* __restrict__ rank_ws) {
    __shared__ int wsum[4];
    __shared__ int cflag[CHUNK];
    __shared__ int crank[CHUNK];

    const int t0 = blockIdx.x * CHUNK;
    const int b  = t0 >> 11;
    const int m0 = t0 & (MM - 1);
    const int* rrow = run + b * MM;
    const int tid  = threadIdx.x;
    const int wave = tid >> 6;
    const int lane = tid & 63;

    // exclusive prefix count of run[b, 0..m0): strided sums + wave shfl reduce
    int s = 0;
    for (int i = tid; i < m0; i += 256) s += (rrow[i] != 0) ? 1 : 0;
#pragma unroll
    for (int off = 32; off > 0; off >>= 1) s += __shfl_xor(s, off, 64);
    if (lane == 0) wsum[wave] = s;
    if (tid < CHUNK) cflag[tid] = (rrow[m0 + tid] != 0) ? 1 : 0;
    __syncthreads();
    const int base0 = wsum[0] + wsum[1] + wsum[2] + wsum[3];
    if (tid < CHUNK) {
        int r = base0;
#pragma unroll
        for (int i = 0; i < CHUNK; ++i) r += (i <= tid) ? cflag[i] : 0;
        crank[tid] = r - 1;
        rank_ws[t0 + tid] = r - 1;
    }
    __syncthreads();

#pragma unroll
    for (int q = 0; q < 2; ++q) {
        const int ti = wave * 2 + q;
        const int t  = t0 + ti;
        const bool r = (cflag[ti] != 0);
        f32x4 hv[4];
        float dot = 0.f;
        if (r) {
            const float* xrow = x + ((size_t)(b * MM + crank[ti])) * HH;
#pragma unroll
            for (int j = 0; j < 4; ++j) {
                const int idx = j * 256 + lane * 4;
                hv[j] = ld4(xrow + idx);
                const f32x4 wv = ld4(p_w + idx);   // L1-hit after first token
                dot += hv[j].x * wv.x + hv[j].y * wv.y +
                       hv[j].z * wv.z + hv[j].w * wv.w;
            }
        } else {
#pragma unroll
            for (int j = 0; j < 4; ++j) hv[j] = (f32x4)(0.f);
        }
#pragma unroll
        for (int off = 32; off > 0; off >>= 1) dot += __shfl_xor(dot, off, 64);

        const float p = r ? (1.f / (1.f + expf(-(dot + p_b[0])))) : 0.f;
        const float ap = acc_p[t];
        const bool mc = r && ((ap + p) < THRESH);
        const bool me = r && !mc;
        const float upd = mc ? p : (me ? (1.f - ap) : 0.f);
        const float ap_new = mc ? (ap + p) : ap;

        const float* whrow = weighted_h + (size_t)t * HH;
        float* orow = out_wh + (size_t)t * HH;
#pragma unroll
        for (int j = 0; j < 4; ++j) {
            const int idx = j * 256 + lane * 4;
            const f32x4 w4 = ntload4(whrow + idx);
            ntstore4(orow + idx, hv[j] * upd + w4);
        }
        if (lane == 0) {
            out_accp[t] = ap_new;
            out_rem[t]  = remainders[t] + (me ? (1.f - ap_new) : 0.f);
            out_run[t]  = mc ? 1.f : 0.f;
            out_exit[t] = (float)(exit_[t] + (me ? (updates[0] + 1) : 0));
            run_new_i[t] = mc ? 1 : 0;
        }
    }
}

// ---------------------------------------------------------------------------
// P2: redundant full-row scan of run_new_i -> rank2/count;
//     scatter-pack x rows (temporal reads, want L3 hits); pad tail (nt).
// ---------------------------------------------------------------------------
__global__ __launch_bounds__(256, 8) void phase2_kernel(
    const float* __restrict__ x, const float* __restrict__ pad_h,
    const int* __restrict__ run_new_i, const int* __restrict__ rank_ws,
    float* __restrict__ h_packed) {
    __shared__ int wsump[4];
    __shared__ int wsuma[4];
    __shared__ int cflag[CHUNK];
    __shared__ int crank2[CHUNK];

    const int t0 = blockIdx.x * CHUNK;
    const int b  = t0 >> 11;
    const int m0 = t0 & (MM - 1);
    const int* nrow = run_new_i + b * MM;
    const int tid  = threadIdx.x;
    const int wave = tid >> 6;
    const int lane = tid & 63;

    int sp = 0, sa = 0;
#pragma unroll
    for (int k = 0; k < MM / 256; ++k) {
        const int i = tid + k * 256;
        const int f = (nrow[i] != 0) ? 1 : 0;
        sa += f;
        if (i < m0) sp += f;
    }
#pragma unroll
    for (int off = 32; off > 0; off >>= 1) {
        sp += __shfl_xor(sp, off, 64);
        sa += __shfl_xor(sa, off, 64);
    }
    if (lane == 0) { wsump[wave] = sp; wsuma[wave] = sa; }
    if (tid < CHUNK) cflag[tid] = (nrow[m0 + tid] != 0) ? 1 : 0;
    __syncthreads();
    const int base0 = wsump[0] + wsump[1] + wsump[2] + wsump[3];
    const int cnt   = wsuma[0] + wsuma[1] + wsuma[2] + wsuma[3];
    if (tid < CHUNK) {
        int r = base0;
#pragma unroll
        for (int i = 0; i < CHUNK; ++i) r += (i <= tid) ? cflag[i] : 0;
        crank2[tid] = r - 1;
    }
    __syncthreads();

#pragma unroll
    for (int q = 0; q < 2; ++q) {
        const int ti = wave * 2 + q;
        const int t  = t0 + ti;
        const int m  = m0 + ti;
        if (cflag[ti] != 0) {
            const float* src = x + ((size_t)(b * MM + rank_ws[t])) * HH;
            float* dst = h_packed + ((size_t)(b * MM + crank2[ti])) * HH;
#pragma unroll
            for (int j = 0; j < 4; ++j) {
                const int idx = j * 256 + lane * 4;
                ntstore4(dst + idx, ld4(src + idx));
            }
        }
        if (m >= cnt) {
            float* prow = h_packed + (size_t)t * HH;
#pragma unroll
            for (int j = 0; j < 4; ++j) {
                const int idx = j * 256 + lane * 4;
                ntstore4(prow + idx, ld4(pad_h + idx));   // pad_h is L1/L2-hit
            }
        }
    }
}

extern "C" void kernel_launch(void* const* d_in, const int* in_sizes, int n_in,
                              void* d_out, int out_size, void* d_ws, size_t ws_size,
                              hipStream_t stream) {
    const float* x          = (const float*)d_in[0];
    const int*   run        = (const int*)d_in[1];
    const float* acc_p      = (const float*)d_in[2];
    const float* weighted_h = (const float*)d_in[3];
    const float* remainders = (const float*)d_in[4];
    const int*   exit_      = (const int*)d_in[5];
    const int*   updates    = (const int*)d_in[6];
    const float* pad_h      = (const float*)d_in[7];
    const float* p_w        = (const float*)d_in[8];
    const float* p_b        = (const float*)d_in[9];

    float* out = (float*)d_out;
    float* out_hpacked = out;                    // [B,M,H]
    float* out_wh      = out + BMH;              // [B,M,H]
    float* out_accp    = out + 2 * BMH;          // [B,M,1]
    float* out_rem     = out_accp + BM;          // [B,M,1]
    float* out_run     = out_rem + BM;           // [B,M]
    float* out_exit    = out_run + BM;           // [B,M,1]

    int* run_new_i = (int*)d_ws;        // [B*M]
    int* rank_ws   = run_new_i + BM;    // [B*M]

    phase1_kernel<<<NBLK, 256, 0, stream>>>(x, run, acc_p, weighted_h, remainders,
                                            exit_, updates, p_w, p_b,
                                            out_wh, out_accp, out_rem, out_run,
                                            out_exit, run_new_i, rank_ws);

    phase2_kernel<<<NBLK, 256, 0, stream>>>(x, pad_h, run_new_i, rank_ws,
                                            out_hpacked);
}